// Round 5
// baseline (380.768 us; speedup 1.0000x reference)
//
#include <hip/hip_runtime.h>

// ---------------- problem constants ----------------
#define NUM_GRAPHS 64
#define NODE_SZ    200
#define FEAT       200
#define HID        256
#define HALF       128
#define N_NODES    (NUM_GRAPHS * NODE_SZ)   // 12800
#define KREAD      (NODE_SZ * HID)          // 51200
#define KSTRIDE    512                      // padded K for conv inputs/weights
#define HBLK       64                       // histogram blocks

typedef unsigned short ushort_t;
typedef unsigned int uint_t;
typedef __attribute__((ext_vector_type(8))) short bf16x8;
typedef __attribute__((ext_vector_type(4))) float f32x4;

__device__ __forceinline__ float bf2f(ushort_t u) {
    union { unsigned int i; float f; } v; v.i = ((unsigned int)u) << 16; return v.f;
}
__device__ __forceinline__ ushort_t f2bf(float f) {
    union { float f; unsigned int i; } v; v.f = f;
    unsigned int x = v.i;
    unsigned int r = (x + 0x7fffu + ((x >> 16) & 1u)) >> 16;  // RNE
    return (ushort_t)r;
}

// ---------------- CSR build (no global atomics) ----------------
// Per-block packed histogram: pos count in low16, neg count in high16.
__global__ __launch_bounds__(1024) void bhist_kernel(const int* __restrict__ ei,
                                                     const float* __restrict__ ew,
                                                     uint_t* __restrict__ bh, int E) {
    __shared__ uint_t h[N_NODES];
    for (int i = threadIdx.x; i < N_NODES; i += 1024) h[i] = 0;
    __syncthreads();
    int b = blockIdx.x;
    int epb = (E + HBLK - 1) / HBLK;
    int e0 = b * epb, e1 = min(e0 + epb, E);
    for (int e = e0 + threadIdx.x; e < e1; e += 1024) {
        int dst = ei[E + e];
        float w = ew[e];
        if (w > 0.0f)      atomicAdd(&h[dst], 1u);
        else if (w < 0.0f) atomicAdd(&h[dst], 0x10000u);
    }
    __syncthreads();
    uint_t* out = bh + (size_t)b * N_NODES;
    for (int i = threadIdx.x * 4; i < N_NODES; i += 4096)
        *(uint4*)&out[i] = *(const uint4*)&h[i];
}

// Column prefix over the 64 block-histograms (in place -> per-block start cursors).
__global__ void colpref_kernel(uint_t* __restrict__ bh, int* __restrict__ counts,
                               int* __restrict__ cnt_p) {
    int n = blockIdx.x * 256 + threadIdx.x;
    if (n >= N_NODES) return;
    uint_t seq = 0;
    for (int b = 0; b < HBLK; ++b) {
        size_t i = (size_t)b * N_NODES + n;
        uint_t v = bh[i];
        bh[i] = seq;
        seq += v;
    }
    counts[n] = (int)((seq & 0xffffu) + (seq >> 16));
    cnt_p[n]  = (int)(seq & 0xffffu);
}

// single block, 1024 threads: exclusive scan of counts -> obnd[n] = {start, start+cnt_p}
__global__ __launch_bounds__(1024) void scan_kernel(const int* __restrict__ counts,
                                                    const int* __restrict__ cnt_p,
                                                    uint2* __restrict__ obnd, int n) {
    const int PER = 13;                       // 1024*13 >= 12800
    int t = threadIdx.x;
    int start = t * PER;
    int local[PER];
    int sum = 0;
#pragma unroll
    for (int i = 0; i < PER; ++i) {
        int idx = start + i;
        int v = (idx < n) ? counts[idx] : 0;
        local[i] = sum;
        sum += v;
    }
    int lane = t & 63, wid = t >> 6;
    int inc = sum;
#pragma unroll
    for (int d = 1; d < 64; d <<= 1) {
        int up = __shfl_up(inc, d);
        if (lane >= d) inc += up;
    }
    __shared__ int wsum[16], woff[16];
    if (lane == 63) wsum[wid] = inc;
    __syncthreads();
    if (t < 16) {
        int acc = 0;
        for (int j = 0; j < 16; ++j) if (j < t) acc += wsum[j];
        woff[t] = acc;
    }
    __syncthreads();
    int base = woff[wid] + (inc - sum);
#pragma unroll
    for (int i = 0; i < PER; ++i) {
        int idx = start + i;
        if (idx < n) {
            uint_t off = (uint_t)(base + local[i]);
            obnd[idx] = make_uint2(off, off + (uint_t)cnt_p[idx]);
        }
    }
    if (t == 1023) {
        uint_t tot = (uint_t)(base + sum);
        obnd[n] = make_uint2(tot, tot);
    }
}

// Scatter with LDS cursors (seeded from per-block prefix). Record = {src, |w|}.
__global__ __launch_bounds__(1024) void scat_kernel(const int* __restrict__ ei,
                                                    const float* __restrict__ ew,
                                                    const uint_t* __restrict__ bh,
                                                    const uint2* __restrict__ obnd,
                                                    uint2* __restrict__ es, int E) {
    __shared__ uint_t cur[N_NODES];
    int b = blockIdx.x;
    const uint_t* pref = bh + (size_t)b * N_NODES;
    for (int i = threadIdx.x * 4; i < N_NODES; i += 4096)
        *(uint4*)&cur[i] = *(const uint4*)&pref[i];
    __syncthreads();
    int epb = (E + HBLK - 1) / HBLK;
    int e0 = b * epb, e1 = min(e0 + epb, E);
    for (int e = e0 + threadIdx.x; e < e1; e += 1024) {
        int src = ei[e];
        int dst = ei[E + e];
        float w = ew[e];
        if (w > 0.0f) {
            uint_t old = atomicAdd(&cur[dst], 1u);
            uint_t pos = obnd[dst].x + (old & 0xffffu);
            es[pos] = make_uint2((uint_t)src, __float_as_uint(w));
        } else if (w < 0.0f) {
            uint_t old = atomicAdd(&cur[dst], 0x10000u);
            uint_t pos = obnd[dst].y + (old >> 16);
            es[pos] = make_uint2((uint_t)src, __float_as_uint(-w));
        }
    }
}

// ---------------- conv weight cast/pad (small, once per call) ----------------
__global__ void castpad_kernel(const float* __restrict__ W, ushort_t* __restrict__ Wb,
                               int K2, int total) {
    int idx = blockIdx.x * 256 + threadIdx.x;
    if (idx >= total) return;
    int row = idx >> 9;
    int col = idx & (KSTRIDE - 1);
    Wb[idx] = (col < K2) ? f2bf(W[(size_t)row * K2 + col]) : (ushort_t)0;
}

// ---------------- signed aggregation: one wave per node, 4 cols per lane ----------------
// Buckets are [positives | negatives]; record = {src, |w|}. deg = bucket widths.
template <int D, bool IN_BF16>
__global__ __launch_bounds__(64) void agg_kernel(const void* __restrict__ hin,
                           const uint2* __restrict__ obnd,
                           const uint2* __restrict__ es,
                           ushort_t* __restrict__ Ap, ushort_t* __restrict__ An) {
    constexpr int ACT = D / 4;
    const float*    hf = (const float*)hin;
    const ushort_t* hb = (const ushort_t*)hin;
    int n = blockIdx.x;
    int lane = threadIdx.x;
    int c0 = lane * 4;
    uint2 ob = obnd[n];
    uint_t off = ob.x, mid = ob.y, end = obnd[n + 1].x;

    __shared__ uint2 s_e[64];

    float ap[4] = {0.f, 0.f, 0.f, 0.f};
    float an[4] = {0.f, 0.f, 0.f, 0.f};

#pragma unroll 1
    for (int phase = 0; phase < 2; ++phase) {
        uint_t lo = phase ? mid : off;
        uint_t hi = phase ? end : mid;
        float* acc = phase ? an : ap;
        for (uint_t base = lo; base < hi; base += 64) {
            int cnt = min(64u, hi - base);
            if (lane < cnt) s_e[lane] = es[base + lane];
            __syncthreads();
            if (lane < ACT) {
                for (int i = 0; i < cnt; ++i) {
                    uint2 r = s_e[i];
                    float w = __uint_as_float(r.y);
                    float v[4];
                    if (IN_BF16) {
                        uint2 pk = *(const uint2*)&hb[(size_t)r.x * D + c0];
                        const ushort_t* p = (const ushort_t*)&pk;
#pragma unroll
                        for (int c = 0; c < 4; ++c) v[c] = bf2f(p[c]);
                    } else {
                        float4 pk = *(const float4*)&hf[(size_t)r.x * D + c0];
                        v[0] = pk.x; v[1] = pk.y; v[2] = pk.z; v[3] = pk.w;
                    }
#pragma unroll
                    for (int c = 0; c < 4; ++c) acc[c] = fmaf(w, v[c], acc[c]);
                }
            }
            __syncthreads();
        }
    }

    size_t rb = (size_t)n * KSTRIDE;
    if (lane < ACT) {
        float dp = fmaxf((float)(mid - off), 1.0f);
        float dn = fmaxf((float)(end - mid), 1.0f);
        ushort4 op, on, os;
        if (IN_BF16) {
            uint2 pk = *(const uint2*)&hb[(size_t)n * D + c0];
            const ushort_t* p = (const ushort_t*)&pk;
            os.x = p[0]; os.y = p[1]; os.z = p[2]; os.w = p[3];
        } else {
            float4 pk = *(const float4*)&hf[(size_t)n * D + c0];
            os.x = f2bf(pk.x); os.y = f2bf(pk.y); os.z = f2bf(pk.z); os.w = f2bf(pk.w);
        }
        op.x = f2bf(ap[0] / dp); op.y = f2bf(ap[1] / dp);
        op.z = f2bf(ap[2] / dp); op.w = f2bf(ap[3] / dp);
        on.x = f2bf(an[0] / dn); on.y = f2bf(an[1] / dn);
        on.z = f2bf(an[2] / dn); on.w = f2bf(an[3] / dn);
        *(ushort4*)&Ap[rb + c0] = op;
        *(ushort4*)&An[rb + c0] = on;
        *(ushort4*)&Ap[rb + D + c0] = os;
        *(ushort4*)&An[rb + D + c0] = os;
    }
    if (D == 200 && lane >= 50 && lane < 54) {   // zero pad cols 400..415
        ushort4 z = {0, 0, 0, 0};
        *(ushort4*)&Ap[rb + 400 + (lane - 50) * 4] = z;
        *(ushort4*)&An[rb + 400 + (lane - 50) * 4] = z;
    }
}

// ---------------- conv linear via MFMA ----------------
// grid.x = M/64, grid.y = 2 (branch). block = 256 (4 waves). Tile 64x128x32.
template <int KSTEPS, bool LEAKY>
__global__ __launch_bounds__(256) void conv_mfma(
        const ushort_t* __restrict__ Ap, const ushort_t* __restrict__ An,
        const ushort_t* __restrict__ Wpb, const ushort_t* __restrict__ Wnb,
        const float* __restrict__ bp, const float* __restrict__ bn,
        ushort_t* __restrict__ hout) {
    __shared__ __align__(16) ushort_t As[64 * 32];    // 4 KB
    __shared__ __align__(16) ushort_t Bs[128 * 32];   // 8 KB
    int mBase = blockIdx.x * 64;
    bool neg = (blockIdx.y != 0);
    const ushort_t* A    = neg ? An : Ap;
    const ushort_t* W    = neg ? Wnb : Wpb;
    const float*    bias = neg ? bn : bp;
    int tid  = threadIdx.x;
    int lane = tid & 63;
    int wv   = tid >> 6;
    int r    = lane & 15;
    int quad = lane >> 4;

    f32x4 acc[8];
#pragma unroll
    for (int j = 0; j < 8; ++j) acc[j] = (f32x4){0.f, 0.f, 0.f, 0.f};

    for (int kt = 0; kt < KSTEPS; ++kt) {
        int kBase = kt * 32;
        {
            int lin = tid * 8;
            int row = lin >> 5, col = lin & 31;
            *(uint4*)&As[lin] = *(const uint4*)&A[(size_t)(mBase + row) * KSTRIDE + kBase + col];
        }
        {
            int l0 = tid * 8;
            int row = l0 >> 5, col = l0 & 31;
            *(uint4*)&Bs[l0] = *(const uint4*)&W[(size_t)row * KSTRIDE + kBase + col];
            int l1 = l0 + 2048;
            row = l1 >> 5; col = l1 & 31;
            *(uint4*)&Bs[l1] = *(const uint4*)&W[(size_t)row * KSTRIDE + kBase + col];
        }
        __syncthreads();
        bf16x8 a = *(const bf16x8*)&As[(wv * 16 + r) * 32 + quad * 8];
#pragma unroll
        for (int j = 0; j < 8; ++j) {
            bf16x8 b = *(const bf16x8*)&Bs[(j * 16 + r) * 32 + quad * 8];
            acc[j] = __builtin_amdgcn_mfma_f32_16x16x32_bf16(a, b, acc[j], 0, 0, 0);
        }
        __syncthreads();
    }
    int colOff = neg ? HALF : 0;
#pragma unroll
    for (int j = 0; j < 8; ++j) {
        int c = j * 16 + r;
        float bv = bias[c];
#pragma unroll
        for (int reg = 0; reg < 4; ++reg) {
            int m = mBase + wv * 16 + quad * 4 + reg;
            float v = acc[j][reg] + bv;
            if (LEAKY) v = (v > 0.0f) ? v : 0.01f * v;
            hout[(size_t)m * HID + colOff + c] = f2bf(v);
        }
    }
}

// ---------------- readout via MFMA, split-K; Wr converted inline fp32->bf16 ----------------
// grid.x = 4 (N tiles of 64), grid.y = 64 (K chunks of 800). block = 256.
__global__ __launch_bounds__(256) void readout_mfma(
        const ushort_t* __restrict__ h, const float* __restrict__ Wr,
        float* __restrict__ g_ws) {
    __shared__ __align__(16) ushort_t As[64 * 32];
    __shared__ __align__(16) ushort_t Bs[64 * 32];
    int nBase  = blockIdx.x * 64;
    int kStart = blockIdx.y * 800;
    int tid  = threadIdx.x;
    int lane = tid & 63;
    int wv   = tid >> 6;
    int r    = lane & 15;
    int quad = lane >> 4;

    f32x4 acc[4];
#pragma unroll
    for (int j = 0; j < 4; ++j) acc[j] = (f32x4){0.f, 0.f, 0.f, 0.f};

    for (int kt = 0; kt < 25; ++kt) {
        int kBase = kStart + kt * 32;
        int lin = tid * 8;
        int row = lin >> 5, col = lin & 31;
        *(uint4*)&As[lin] = *(const uint4*)&h[(size_t)row * KREAD + kBase + col];
        {
            const float* wp = &Wr[(size_t)(nBase + row) * KREAD + kBase + col];
            float4 f0 = *(const float4*)&wp[0];
            float4 f1 = *(const float4*)&wp[4];
            ushort4 b0, b1;
            b0.x = f2bf(f0.x); b0.y = f2bf(f0.y); b0.z = f2bf(f0.z); b0.w = f2bf(f0.w);
            b1.x = f2bf(f1.x); b1.y = f2bf(f1.y); b1.z = f2bf(f1.z); b1.w = f2bf(f1.w);
            *(ushort4*)&Bs[lin]     = b0;
            *(ushort4*)&Bs[lin + 4] = b1;
        }
        __syncthreads();
        bf16x8 a = *(const bf16x8*)&As[(wv * 16 + r) * 32 + quad * 8];
#pragma unroll
        for (int j = 0; j < 4; ++j) {
            bf16x8 b = *(const bf16x8*)&Bs[(j * 16 + r) * 32 + quad * 8];
            acc[j] = __builtin_amdgcn_mfma_f32_16x16x32_bf16(a, b, acc[j], 0, 0, 0);
        }
        __syncthreads();
    }
#pragma unroll
    for (int j = 0; j < 4; ++j) {
        int c = nBase + j * 16 + r;
#pragma unroll
        for (int reg = 0; reg < 4; ++reg) {
            int g = wv * 16 + quad * 4 + reg;
            atomicAdd(&g_ws[g * HID + c], acc[j][reg]);
        }
    }
}

// ---------------- final: out[g] = sum_c (g_ws+br)*Wl + bl ----------------
__global__ void final_kernel(const float* __restrict__ g_ws, const float* __restrict__ br,
                             const float* __restrict__ Wl, const float* __restrict__ bl,
                             float* __restrict__ out) {
    int g = blockIdx.x;
    int c = threadIdx.x;   // 256
    float v = (g_ws[g * HID + c] + br[c]) * Wl[c];
#pragma unroll
    for (int d = 32; d > 0; d >>= 1) v += __shfl_down(v, d);
    __shared__ float s[4];
    if ((c & 63) == 0) s[c >> 6] = v;
    __syncthreads();
    if (c == 0) out[g] = s[0] + s[1] + s[2] + s[3] + bl[0];
}

// ---------------- launch ----------------
extern "C" void kernel_launch(void* const* d_in, const int* in_sizes, int n_in,
                              void* d_out, int out_size, void* d_ws, size_t ws_size,
                              hipStream_t stream) {
    const float* x  = (const float*)d_in[0];
    const int*   ei = (const int*)d_in[1];
    const float* ew = (const float*)d_in[2];
    // d_in[3] = batch (unused; graphs are contiguous)
    const float* Wp0 = (const float*)d_in[4];
    const float* bp0 = (const float*)d_in[5];
    const float* Wn0 = (const float*)d_in[6];
    const float* bn0 = (const float*)d_in[7];
    const float* Wp1 = (const float*)d_in[8];
    const float* bp1 = (const float*)d_in[9];
    const float* Wn1 = (const float*)d_in[10];
    const float* bn1 = (const float*)d_in[11];
    const float* Wp2 = (const float*)d_in[12];
    const float* bp2 = (const float*)d_in[13];
    const float* Wn2 = (const float*)d_in[14];
    const float* bn2 = (const float*)d_in[15];
    const float* Wr  = (const float*)d_in[16];
    const float* br  = (const float*)d_in[17];
    const float* Wl  = (const float*)d_in[18];
    const float* bl  = (const float*)d_in[19];
    const int E = in_sizes[1] / 2;   // 409600

    // ---- workspace layout (bytes) ----
    char* ws = (char*)d_ws;
    float*    g_ws   = (float*)(ws + 0);             // 64*256 fp32 = 65536 (memset region)
    uint_t*   bh     = (uint_t*)(ws + 65536);        // 64*12800 u32 = 3276800 -> 3342336
    int*      counts = (int*)(ws + 3342336);         // 51200 -> 3393536
    int*      cnt_p  = (int*)(ws + 3393536);         // 51200 -> 3444736
    uint2*    obnd   = (uint2*)(ws + 3444736);       // 12801*8 (reserve 102464) -> 3547200
    uint2*    es     = (uint2*)(ws + 3547200);       // E*8 = 3276800 -> 6824000
    ushort_t* Ap     = (ushort_t*)(ws + 6824000);    // 12800*512 bf16 = 13107200 -> 19931200
    ushort_t* An     = (ushort_t*)(ws + 19931200);   // -> 33038400
    ushort_t* hA     = (ushort_t*)(ws + 33038400);   // 12800*256 bf16 = 6553600 -> 39592000
    ushort_t* hB     = (ushort_t*)(ws + 39592000);   // -> 46145600
    ushort_t* wcast  = (ushort_t*)(ws + 46145600);   // 6 x 65536 bf16 = 786432 -> 46932032

    ushort_t* w0p = wcast + 0 * 65536;
    ushort_t* w0n = wcast + 1 * 65536;
    ushort_t* w1p = wcast + 2 * 65536;
    ushort_t* w1n = wcast + 3 * 65536;
    ushort_t* w2p = wcast + 4 * 65536;
    ushort_t* w2n = wcast + 5 * 65536;

    hipMemsetAsync(g_ws, 0, 65536, stream);   // only g_ws needs zeroing

    // CSR build
    hipLaunchKernelGGL(bhist_kernel, dim3(HBLK), dim3(1024), 0, stream, ei, ew, bh, E);
    hipLaunchKernelGGL(colpref_kernel, dim3((N_NODES + 255) / 256), dim3(256), 0, stream,
                       bh, counts, cnt_p);
    hipLaunchKernelGGL(scan_kernel, dim3(1), dim3(1024), 0, stream, counts, cnt_p, obnd, N_NODES);
    hipLaunchKernelGGL(scat_kernel, dim3(HBLK), dim3(1024), 0, stream, ei, ew, bh, obnd, es, E);

    // conv weight casts (small; independent of CSR)
    const int wtot = HALF * KSTRIDE;                 // 65536
    hipLaunchKernelGGL(castpad_kernel, dim3(wtot / 256), dim3(256), 0, stream, Wp0, w0p, 400, wtot);
    hipLaunchKernelGGL(castpad_kernel, dim3(wtot / 256), dim3(256), 0, stream, Wn0, w0n, 400, wtot);
    hipLaunchKernelGGL(castpad_kernel, dim3(wtot / 256), dim3(256), 0, stream, Wp1, w1p, 512, wtot);
    hipLaunchKernelGGL(castpad_kernel, dim3(wtot / 256), dim3(256), 0, stream, Wn1, w1n, 512, wtot);
    hipLaunchKernelGGL(castpad_kernel, dim3(wtot / 256), dim3(256), 0, stream, Wp2, w2p, 512, wtot);
    hipLaunchKernelGGL(castpad_kernel, dim3(wtot / 256), dim3(256), 0, stream, Wn2, w2n, 512, wtot);

    // layer 0: in = x (fp32, D=200), KSTEPS = 13 (covers padded 416)
    hipLaunchKernelGGL((agg_kernel<FEAT, false>), dim3(N_NODES), dim3(64), 0, stream,
                       (const void*)x, obnd, es, Ap, An);
    hipLaunchKernelGGL((conv_mfma<13, true>), dim3(N_NODES / 64, 2), dim3(256), 0, stream,
                       Ap, An, w0p, w0n, bp0, bn0, hA);
    // layer 1: in = hA (bf16, D=256), KSTEPS = 16
    hipLaunchKernelGGL((agg_kernel<HID, true>), dim3(N_NODES), dim3(64), 0, stream,
                       (const void*)hA, obnd, es, Ap, An);
    hipLaunchKernelGGL((conv_mfma<16, true>), dim3(N_NODES / 64, 2), dim3(256), 0, stream,
                       Ap, An, w1p, w1n, bp1, bn1, hB);
    // layer 2: in = hB, no activation
    hipLaunchKernelGGL((agg_kernel<HID, true>), dim3(N_NODES), dim3(64), 0, stream,
                       (const void*)hB, obnd, es, Ap, An);
    hipLaunchKernelGGL((conv_mfma<16, false>), dim3(N_NODES / 64, 2), dim3(256), 0, stream,
                       Ap, An, w2p, w2n, bp2, bn2, hA);

    // readout + final
    hipLaunchKernelGGL(readout_mfma, dim3(4, 64), dim3(256), 0, stream, hA, Wr, g_ws);
    hipLaunchKernelGGL(final_kernel, dim3(NUM_GRAPHS), dim3(256), 0, stream,
                       g_ws, br, Wl, bl, (float*)d_out);
}

// Round 6
// 343.843 us; speedup vs baseline: 1.1074x; 1.1074x over previous
//
#include <hip/hip_runtime.h>

// ---------------- problem constants ----------------
#define NUM_GRAPHS 64
#define NODE_SZ    200
#define FEAT       200
#define HID        256
#define HALF       128
#define N_NODES    (NUM_GRAPHS * NODE_SZ)   // 12800
#define KREAD      (NODE_SZ * HID)          // 51200
#define KSTRIDE    512                      // padded K for conv inputs/weights
#define HBLK       64                       // histogram blocks

typedef unsigned short ushort_t;
typedef unsigned int uint_t;
typedef __attribute__((ext_vector_type(8))) short bf16x8;
typedef __attribute__((ext_vector_type(4))) float f32x4;

__device__ __forceinline__ float bf2f(ushort_t u) {
    union { unsigned int i; float f; } v; v.i = ((unsigned int)u) << 16; return v.f;
}
__device__ __forceinline__ ushort_t f2bf(float f) {
    union { float f; unsigned int i; } v; v.f = f;
    unsigned int x = v.i;
    unsigned int r = (x + 0x7fffu + ((x >> 16) & 1u)) >> 16;  // RNE
    return (ushort_t)r;
}

// ---------------- CSR build (no global atomics) ----------------
__global__ __launch_bounds__(1024) void bhist_kernel(const int* __restrict__ ei,
                                                     const float* __restrict__ ew,
                                                     uint_t* __restrict__ bh, int E) {
    __shared__ uint_t h[N_NODES];
    for (int i = threadIdx.x; i < N_NODES; i += 1024) h[i] = 0;
    __syncthreads();
    int b = blockIdx.x;
    int epb = (E + HBLK - 1) / HBLK;
    int e0 = b * epb, e1 = min(e0 + epb, E);
    for (int e = e0 + threadIdx.x; e < e1; e += 1024) {
        int dst = ei[E + e];
        float w = ew[e];
        if (w > 0.0f)      atomicAdd(&h[dst], 1u);
        else if (w < 0.0f) atomicAdd(&h[dst], 0x10000u);
    }
    __syncthreads();
    uint_t* out = bh + (size_t)b * N_NODES;
    for (int i = threadIdx.x * 4; i < N_NODES; i += 4096)
        *(uint4*)&out[i] = *(const uint4*)&h[i];
}

__global__ void colpref_kernel(uint_t* __restrict__ bh, int* __restrict__ counts,
                               int* __restrict__ cnt_p) {
    int n = blockIdx.x * 256 + threadIdx.x;
    if (n >= N_NODES) return;
    uint_t seq = 0;
    for (int b = 0; b < HBLK; ++b) {
        size_t i = (size_t)b * N_NODES + n;
        uint_t v = bh[i];
        bh[i] = seq;
        seq += v;
    }
    counts[n] = (int)((seq & 0xffffu) + (seq >> 16));
    cnt_p[n]  = (int)(seq & 0xffffu);
}

__global__ __launch_bounds__(1024) void scan_kernel(const int* __restrict__ counts,
                                                    const int* __restrict__ cnt_p,
                                                    uint2* __restrict__ obnd, int n) {
    const int PER = 13;
    int t = threadIdx.x;
    int start = t * PER;
    int local[PER];
    int sum = 0;
#pragma unroll
    for (int i = 0; i < PER; ++i) {
        int idx = start + i;
        int v = (idx < n) ? counts[idx] : 0;
        local[i] = sum;
        sum += v;
    }
    int lane = t & 63, wid = t >> 6;
    int inc = sum;
#pragma unroll
    for (int d = 1; d < 64; d <<= 1) {
        int up = __shfl_up(inc, d);
        if (lane >= d) inc += up;
    }
    __shared__ int wsum[16], woff[16];
    if (lane == 63) wsum[wid] = inc;
    __syncthreads();
    if (t < 16) {
        int acc = 0;
        for (int j = 0; j < 16; ++j) if (j < t) acc += wsum[j];
        woff[t] = acc;
    }
    __syncthreads();
    int base = woff[wid] + (inc - sum);
#pragma unroll
    for (int i = 0; i < PER; ++i) {
        int idx = start + i;
        if (idx < n) {
            uint_t off = (uint_t)(base + local[i]);
            obnd[idx] = make_uint2(off, off + (uint_t)cnt_p[idx]);
        }
    }
    if (t == 1023) {
        uint_t tot = (uint_t)(base + sum);
        obnd[n] = make_uint2(tot, tot);
    }
}

__global__ __launch_bounds__(1024) void scat_kernel(const int* __restrict__ ei,
                                                    const float* __restrict__ ew,
                                                    const uint_t* __restrict__ bh,
                                                    const uint2* __restrict__ obnd,
                                                    uint2* __restrict__ es, int E) {
    __shared__ uint_t cur[N_NODES];
    int b = blockIdx.x;
    const uint_t* pref = bh + (size_t)b * N_NODES;
    for (int i = threadIdx.x * 4; i < N_NODES; i += 4096)
        *(uint4*)&cur[i] = *(const uint4*)&pref[i];
    __syncthreads();
    int epb = (E + HBLK - 1) / HBLK;
    int e0 = b * epb, e1 = min(e0 + epb, E);
    for (int e = e0 + threadIdx.x; e < e1; e += 1024) {
        int src = ei[e];
        int dst = ei[E + e];
        float w = ew[e];
        if (w > 0.0f) {
            uint_t old = atomicAdd(&cur[dst], 1u);
            uint_t pos = obnd[dst].x + (old & 0xffffu);
            es[pos] = make_uint2((uint_t)src, __float_as_uint(w));
        } else if (w < 0.0f) {
            uint_t old = atomicAdd(&cur[dst], 0x10000u);
            uint_t pos = obnd[dst].y + (old >> 16);
            es[pos] = make_uint2((uint_t)src, __float_as_uint(-w));
        }
    }
}

// ---------------- casts ----------------
__global__ void castpad_kernel(const float* __restrict__ W, ushort_t* __restrict__ Wb,
                               int K2, int total) {
    int idx = blockIdx.x * 256 + threadIdx.x;
    if (idx >= total) return;
    int row = idx >> 9;
    int col = idx & (KSTRIDE - 1);
    Wb[idx] = (col < K2) ? f2bf(W[(size_t)row * K2 + col]) : (ushort_t)0;
}

__global__ void cast_kernel(const float* __restrict__ X, ushort_t* __restrict__ Xb, int n) {
    int i = (blockIdx.x * 256 + threadIdx.x) * 4;
    if (i >= n) return;
    float4 v = *(const float4*)&X[i];
    ushort4 o;
    o.x = f2bf(v.x); o.y = f2bf(v.y); o.z = f2bf(v.z); o.w = f2bf(v.w);
    *(ushort4*)&Xb[i] = o;
}

// ---------------- signed aggregation: 4 waves/block, one node per wave ----------------
// All-bf16 input. Edge records broadcast via shfl; 4-edge batched row loads.
template <int D>
__global__ __launch_bounds__(256) void agg_kernel(
        const ushort_t* __restrict__ hb,
        const uint2* __restrict__ obnd,
        const uint2* __restrict__ es,
        ushort_t* __restrict__ Ap, ushort_t* __restrict__ An) {
    constexpr int ACT = D / 4;
    int lane = threadIdx.x & 63;
    int wv   = threadIdx.x >> 6;
    int n = blockIdx.x * 4 + wv;
    int c0 = min(lane, ACT - 1) * 4;       // clamped for idle lanes (D=200)
    uint2 ob = obnd[n];
    uint_t off = ob.x, mid = ob.y, end = obnd[n + 1].x;

    float ap[4] = {0.f, 0.f, 0.f, 0.f};
    float an[4] = {0.f, 0.f, 0.f, 0.f};

#pragma unroll 1
    for (int phase = 0; phase < 2; ++phase) {
        uint_t lo = phase ? mid : off;
        uint_t hi = phase ? end : mid;
        float* acc = phase ? an : ap;
#pragma unroll 1
        for (uint_t base = lo; base < hi; base += 64) {
            int cnt = (int)min(64u, hi - base);
            uint2 rec = es[base + (uint_t)min(lane, cnt - 1)];
            int i = 0;
#pragma unroll 1
            for (; i + 4 <= cnt; i += 4) {
                int s0 = __shfl((int)rec.x, i);
                int s1 = __shfl((int)rec.x, i + 1);
                int s2 = __shfl((int)rec.x, i + 2);
                int s3 = __shfl((int)rec.x, i + 3);
                float w0 = __uint_as_float((uint_t)__shfl((int)rec.y, i));
                float w1 = __uint_as_float((uint_t)__shfl((int)rec.y, i + 1));
                float w2 = __uint_as_float((uint_t)__shfl((int)rec.y, i + 2));
                float w3 = __uint_as_float((uint_t)__shfl((int)rec.y, i + 3));
                uint2 p0 = *(const uint2*)&hb[(size_t)s0 * D + c0];
                uint2 p1 = *(const uint2*)&hb[(size_t)s1 * D + c0];
                uint2 p2 = *(const uint2*)&hb[(size_t)s2 * D + c0];
                uint2 p3 = *(const uint2*)&hb[(size_t)s3 * D + c0];
                const ushort_t* q0 = (const ushort_t*)&p0;
                const ushort_t* q1 = (const ushort_t*)&p1;
                const ushort_t* q2 = (const ushort_t*)&p2;
                const ushort_t* q3 = (const ushort_t*)&p3;
#pragma unroll
                for (int c = 0; c < 4; ++c) acc[c] = fmaf(w0, bf2f(q0[c]), acc[c]);
#pragma unroll
                for (int c = 0; c < 4; ++c) acc[c] = fmaf(w1, bf2f(q1[c]), acc[c]);
#pragma unroll
                for (int c = 0; c < 4; ++c) acc[c] = fmaf(w2, bf2f(q2[c]), acc[c]);
#pragma unroll
                for (int c = 0; c < 4; ++c) acc[c] = fmaf(w3, bf2f(q3[c]), acc[c]);
            }
#pragma unroll 1
            for (; i < cnt; ++i) {
                int s = __shfl((int)rec.x, i);
                float w = __uint_as_float((uint_t)__shfl((int)rec.y, i));
                uint2 pk = *(const uint2*)&hb[(size_t)s * D + c0];
                const ushort_t* q = (const ushort_t*)&pk;
#pragma unroll
                for (int c = 0; c < 4; ++c) acc[c] = fmaf(w, bf2f(q[c]), acc[c]);
            }
        }
    }

    size_t rb = (size_t)n * KSTRIDE;
    if (lane < ACT) {
        float dp = fmaxf((float)(mid - off), 1.0f);
        float dn = fmaxf((float)(end - mid), 1.0f);
        uint2 pk = *(const uint2*)&hb[(size_t)n * D + c0];
        const ushort_t* p = (const ushort_t*)&pk;
        ushort4 os = {p[0], p[1], p[2], p[3]};
        ushort4 op, on;
        op.x = f2bf(ap[0] / dp); op.y = f2bf(ap[1] / dp);
        op.z = f2bf(ap[2] / dp); op.w = f2bf(ap[3] / dp);
        on.x = f2bf(an[0] / dn); on.y = f2bf(an[1] / dn);
        on.z = f2bf(an[2] / dn); on.w = f2bf(an[3] / dn);
        *(ushort4*)&Ap[rb + c0] = op;
        *(ushort4*)&An[rb + c0] = on;
        *(ushort4*)&Ap[rb + D + c0] = os;
        *(ushort4*)&An[rb + D + c0] = os;
    }
    if (D == 200 && lane >= 50 && lane < 54) {   // zero pad cols 400..415
        ushort4 z = {0, 0, 0, 0};
        *(ushort4*)&Ap[rb + 400 + (lane - 50) * 4] = z;
        *(ushort4*)&An[rb + 400 + (lane - 50) * 4] = z;
    }
}

// ---------------- conv linear via MFMA ----------------
template <int KSTEPS, bool LEAKY>
__global__ __launch_bounds__(256) void conv_mfma(
        const ushort_t* __restrict__ Ap, const ushort_t* __restrict__ An,
        const ushort_t* __restrict__ Wpb, const ushort_t* __restrict__ Wnb,
        const float* __restrict__ bp, const float* __restrict__ bn,
        ushort_t* __restrict__ hout) {
    __shared__ __align__(16) ushort_t As[64 * 32];
    __shared__ __align__(16) ushort_t Bs[128 * 32];
    int mBase = blockIdx.x * 64;
    bool neg = (blockIdx.y != 0);
    const ushort_t* A    = neg ? An : Ap;
    const ushort_t* W    = neg ? Wnb : Wpb;
    const float*    bias = neg ? bn : bp;
    int tid  = threadIdx.x;
    int lane = tid & 63;
    int wv   = tid >> 6;
    int r    = lane & 15;
    int quad = lane >> 4;

    f32x4 acc[8];
#pragma unroll
    for (int j = 0; j < 8; ++j) acc[j] = (f32x4){0.f, 0.f, 0.f, 0.f};

    for (int kt = 0; kt < KSTEPS; ++kt) {
        int kBase = kt * 32;
        {
            int lin = tid * 8;
            int row = lin >> 5, col = lin & 31;
            *(uint4*)&As[lin] = *(const uint4*)&A[(size_t)(mBase + row) * KSTRIDE + kBase + col];
        }
        {
            int l0 = tid * 8;
            int row = l0 >> 5, col = l0 & 31;
            *(uint4*)&Bs[l0] = *(const uint4*)&W[(size_t)row * KSTRIDE + kBase + col];
            int l1 = l0 + 2048;
            row = l1 >> 5; col = l1 & 31;
            *(uint4*)&Bs[l1] = *(const uint4*)&W[(size_t)row * KSTRIDE + kBase + col];
        }
        __syncthreads();
        bf16x8 a = *(const bf16x8*)&As[(wv * 16 + r) * 32 + quad * 8];
#pragma unroll
        for (int j = 0; j < 8; ++j) {
            bf16x8 b = *(const bf16x8*)&Bs[(j * 16 + r) * 32 + quad * 8];
            acc[j] = __builtin_amdgcn_mfma_f32_16x16x32_bf16(a, b, acc[j], 0, 0, 0);
        }
        __syncthreads();
    }
    int colOff = neg ? HALF : 0;
#pragma unroll
    for (int j = 0; j < 8; ++j) {
        int c = j * 16 + r;
        float bv = bias[c];
#pragma unroll
        for (int reg = 0; reg < 4; ++reg) {
            int m = mBase + wv * 16 + quad * 4 + reg;
            float v = acc[j][reg] + bv;
            if (LEAKY) v = (v > 0.0f) ? v : 0.01f * v;
            hout[(size_t)m * HID + colOff + c] = f2bf(v);
        }
    }
}

// ---------------- readout via MFMA, split-K; Wr converted inline fp32->bf16 ----------------
__global__ __launch_bounds__(256) void readout_mfma(
        const ushort_t* __restrict__ h, const float* __restrict__ Wr,
        float* __restrict__ g_ws) {
    __shared__ __align__(16) ushort_t As[64 * 32];
    __shared__ __align__(16) ushort_t Bs[64 * 32];
    int nBase  = blockIdx.x * 64;
    int kStart = blockIdx.y * 800;
    int tid  = threadIdx.x;
    int lane = tid & 63;
    int wv   = tid >> 6;
    int r    = lane & 15;
    int quad = lane >> 4;

    f32x4 acc[4];
#pragma unroll
    for (int j = 0; j < 4; ++j) acc[j] = (f32x4){0.f, 0.f, 0.f, 0.f};

    for (int kt = 0; kt < 25; ++kt) {
        int kBase = kStart + kt * 32;
        int lin = tid * 8;
        int row = lin >> 5, col = lin & 31;
        *(uint4*)&As[lin] = *(const uint4*)&h[(size_t)row * KREAD + kBase + col];
        {
            const float* wp = &Wr[(size_t)(nBase + row) * KREAD + kBase + col];
            float4 f0 = *(const float4*)&wp[0];
            float4 f1 = *(const float4*)&wp[4];
            ushort4 b0, b1;
            b0.x = f2bf(f0.x); b0.y = f2bf(f0.y); b0.z = f2bf(f0.z); b0.w = f2bf(f0.w);
            b1.x = f2bf(f1.x); b1.y = f2bf(f1.y); b1.z = f2bf(f1.z); b1.w = f2bf(f1.w);
            *(ushort4*)&Bs[lin]     = b0;
            *(ushort4*)&Bs[lin + 4] = b1;
        }
        __syncthreads();
        bf16x8 a = *(const bf16x8*)&As[(wv * 16 + r) * 32 + quad * 8];
#pragma unroll
        for (int j = 0; j < 4; ++j) {
            bf16x8 b = *(const bf16x8*)&Bs[(j * 16 + r) * 32 + quad * 8];
            acc[j] = __builtin_amdgcn_mfma_f32_16x16x32_bf16(a, b, acc[j], 0, 0, 0);
        }
        __syncthreads();
    }
#pragma unroll
    for (int j = 0; j < 4; ++j) {
        int c = nBase + j * 16 + r;
#pragma unroll
        for (int reg = 0; reg < 4; ++reg) {
            int g = wv * 16 + quad * 4 + reg;
            atomicAdd(&g_ws[g * HID + c], acc[j][reg]);
        }
    }
}

// ---------------- final ----------------
__global__ void final_kernel(const float* __restrict__ g_ws, const float* __restrict__ br,
                             const float* __restrict__ Wl, const float* __restrict__ bl,
                             float* __restrict__ out) {
    int g = blockIdx.x;
    int c = threadIdx.x;
    float v = (g_ws[g * HID + c] + br[c]) * Wl[c];
#pragma unroll
    for (int d = 32; d > 0; d >>= 1) v += __shfl_down(v, d);
    __shared__ float s[4];
    if ((c & 63) == 0) s[c >> 6] = v;
    __syncthreads();
    if (c == 0) out[g] = s[0] + s[1] + s[2] + s[3] + bl[0];
}

// ---------------- launch ----------------
extern "C" void kernel_launch(void* const* d_in, const int* in_sizes, int n_in,
                              void* d_out, int out_size, void* d_ws, size_t ws_size,
                              hipStream_t stream) {
    const float* x  = (const float*)d_in[0];
    const int*   ei = (const int*)d_in[1];
    const float* ew = (const float*)d_in[2];
    const float* Wp0 = (const float*)d_in[4];
    const float* bp0 = (const float*)d_in[5];
    const float* Wn0 = (const float*)d_in[6];
    const float* bn0 = (const float*)d_in[7];
    const float* Wp1 = (const float*)d_in[8];
    const float* bp1 = (const float*)d_in[9];
    const float* Wn1 = (const float*)d_in[10];
    const float* bn1 = (const float*)d_in[11];
    const float* Wp2 = (const float*)d_in[12];
    const float* bp2 = (const float*)d_in[13];
    const float* Wn2 = (const float*)d_in[14];
    const float* bn2 = (const float*)d_in[15];
    const float* Wr  = (const float*)d_in[16];
    const float* br  = (const float*)d_in[17];
    const float* Wl  = (const float*)d_in[18];
    const float* bl  = (const float*)d_in[19];
    const int E = in_sizes[1] / 2;   // 409600

    // ---- workspace layout (bytes) ----
    char* ws = (char*)d_ws;
    float*    g_ws   = (float*)(ws + 0);             // 65536 (memset region)
    uint_t*   bh     = (uint_t*)(ws + 65536);        // 64*12800 u32 -> 3342336
    int*      counts = (int*)(ws + 3342336);         // -> 3393536
    int*      cnt_p  = (int*)(ws + 3393536);         // -> 3444736
    uint2*    obnd   = (uint2*)(ws + 3444736);       // -> 3547200
    uint2*    es     = (uint2*)(ws + 3547200);       // E*8 -> 6824000
    ushort_t* Ap     = (ushort_t*)(ws + 6824000);    // 12800*512 bf16 -> 19931200
    ushort_t* An     = (ushort_t*)(ws + 19931200);   // -> 33038400
    ushort_t* hA     = (ushort_t*)(ws + 33038400);   // 12800*256 bf16 -> 39592000
    ushort_t* hB     = (ushort_t*)(ws + 39592000);   // -> 46145600
    ushort_t* wcast  = (ushort_t*)(ws + 46145600);   // 6 x 65536 bf16 -> 46932032
    ushort_t* xb     = (ushort_t*)(ws + 46932032);   // 12800*200 bf16 + pad -> 52052160

    ushort_t* w0p = wcast + 0 * 65536;
    ushort_t* w0n = wcast + 1 * 65536;
    ushort_t* w1p = wcast + 2 * 65536;
    ushort_t* w1n = wcast + 3 * 65536;
    ushort_t* w2p = wcast + 4 * 65536;
    ushort_t* w2n = wcast + 5 * 65536;

    hipMemsetAsync(g_ws, 0, 65536, stream);

    // CSR build
    hipLaunchKernelGGL(bhist_kernel, dim3(HBLK), dim3(1024), 0, stream, ei, ew, bh, E);
    hipLaunchKernelGGL(colpref_kernel, dim3((N_NODES + 255) / 256), dim3(256), 0, stream,
                       bh, counts, cnt_p);
    hipLaunchKernelGGL(scan_kernel, dim3(1), dim3(1024), 0, stream, counts, cnt_p, obnd, N_NODES);
    hipLaunchKernelGGL(scat_kernel, dim3(HBLK), dim3(1024), 0, stream, ei, ew, bh, obnd, es, E);

    // casts
    const int wtot = HALF * KSTRIDE;
    hipLaunchKernelGGL(castpad_kernel, dim3(wtot / 256), dim3(256), 0, stream, Wp0, w0p, 400, wtot);
    hipLaunchKernelGGL(castpad_kernel, dim3(wtot / 256), dim3(256), 0, stream, Wn0, w0n, 400, wtot);
    hipLaunchKernelGGL(castpad_kernel, dim3(wtot / 256), dim3(256), 0, stream, Wp1, w1p, 512, wtot);
    hipLaunchKernelGGL(castpad_kernel, dim3(wtot / 256), dim3(256), 0, stream, Wn1, w1n, 512, wtot);
    hipLaunchKernelGGL(castpad_kernel, dim3(wtot / 256), dim3(256), 0, stream, Wp2, w2p, 512, wtot);
    hipLaunchKernelGGL(castpad_kernel, dim3(wtot / 256), dim3(256), 0, stream, Wn2, w2n, 512, wtot);
    hipLaunchKernelGGL(cast_kernel, dim3((N_NODES * FEAT / 4 + 255) / 256), dim3(256), 0, stream,
                       x, xb, N_NODES * FEAT);

    // layer 0: in = xb (bf16, D=200), KSTEPS = 13 (covers padded 416)
    hipLaunchKernelGGL((agg_kernel<FEAT>), dim3(N_NODES / 4), dim3(256), 0, stream,
                       xb, obnd, es, Ap, An);
    hipLaunchKernelGGL((conv_mfma<13, true>), dim3(N_NODES / 64, 2), dim3(256), 0, stream,
                       Ap, An, w0p, w0n, bp0, bn0, hA);
    // layer 1
    hipLaunchKernelGGL((agg_kernel<HID>), dim3(N_NODES / 4), dim3(256), 0, stream,
                       hA, obnd, es, Ap, An);
    hipLaunchKernelGGL((conv_mfma<16, true>), dim3(N_NODES / 64, 2), dim3(256), 0, stream,
                       Ap, An, w1p, w1n, bp1, bn1, hB);
    // layer 2
    hipLaunchKernelGGL((agg_kernel<HID>), dim3(N_NODES / 4), dim3(256), 0, stream,
                       hB, obnd, es, Ap, An);
    hipLaunchKernelGGL((conv_mfma<16, false>), dim3(N_NODES / 64, 2), dim3(256), 0, stream,
                       Ap, An, w2p, w2n, bp2, bn2, hA);

    // readout + final
    hipLaunchKernelGGL(readout_mfma, dim3(4, 64), dim3(256), 0, stream, hA, Wr, g_ws);
    hipLaunchKernelGGL(final_kernel, dim3(NUM_GRAPHS), dim3(256), 0, stream,
                       g_ws, br, Wl, bl, (float*)d_out);
}

// Round 7
// 315.189 us; speedup vs baseline: 1.2081x; 1.0909x over previous
//
#include <hip/hip_runtime.h>

// ---------------- problem constants ----------------
#define NUM_GRAPHS 64
#define NODE_SZ    200
#define FEAT       200
#define HID        256
#define HALF       128
#define N_NODES    (NUM_GRAPHS * NODE_SZ)   // 12800
#define KREAD      (NODE_SZ * HID)          // 51200
#define KSTRIDE    512                      // padded K for conv inputs/weights
#define HBLK       128                      // histogram/scatter blocks

typedef unsigned short ushort_t;
typedef unsigned int uint_t;
typedef __attribute__((ext_vector_type(8))) short bf16x8;
typedef __attribute__((ext_vector_type(4))) float f32x4;

#define GAS(p) ((const __attribute__((address_space(1))) void*)(p))
#define LAS(p) ((__attribute__((address_space(3))) void*)(p))

__device__ __forceinline__ float bf2f(ushort_t u) {
    union { unsigned int i; float f; } v; v.i = ((unsigned int)u) << 16; return v.f;
}
__device__ __forceinline__ ushort_t f2bf(float f) {
    union { float f; unsigned int i; } v; v.f = f;
    unsigned int x = v.i;
    unsigned int r = (x + 0x7fffu + ((x >> 16) & 1u)) >> 16;  // RNE
    return (ushort_t)r;
}

// ---------------- CSR build (no global atomics) ----------------
__global__ __launch_bounds__(1024) void bhist_kernel(const int* __restrict__ ei,
                                                     const float* __restrict__ ew,
                                                     uint_t* __restrict__ bh, int E) {
    __shared__ uint_t h[N_NODES];
    for (int i = threadIdx.x; i < N_NODES; i += 1024) h[i] = 0;
    __syncthreads();
    int b = blockIdx.x;
    int epb = (E + HBLK - 1) / HBLK;
    int e0 = b * epb, e1 = min(e0 + epb, E);
    for (int e = e0 + threadIdx.x; e < e1; e += 1024) {
        int dst = ei[E + e];
        float w = ew[e];
        if (w > 0.0f)      atomicAdd(&h[dst], 1u);
        else if (w < 0.0f) atomicAdd(&h[dst], 0x10000u);
    }
    __syncthreads();
    uint_t* out = bh + (size_t)b * N_NODES;
    for (int i = threadIdx.x * 4; i < N_NODES; i += 4096)
        *(uint4*)&out[i] = *(const uint4*)&h[i];
}

__global__ void colpref_kernel(uint_t* __restrict__ bh, int* __restrict__ counts,
                               int* __restrict__ cnt_p) {
    int n = blockIdx.x * 256 + threadIdx.x;
    if (n >= N_NODES) return;
    uint_t seq = 0;
    for (int b = 0; b < HBLK; ++b) {
        size_t i = (size_t)b * N_NODES + n;
        uint_t v = bh[i];
        bh[i] = seq;
        seq += v;
    }
    counts[n] = (int)((seq & 0xffffu) + (seq >> 16));
    cnt_p[n]  = (int)(seq & 0xffffu);
}

__global__ __launch_bounds__(1024) void scan_kernel(const int* __restrict__ counts,
                                                    const int* __restrict__ cnt_p,
                                                    uint2* __restrict__ obnd, int n) {
    const int PER = 13;
    int t = threadIdx.x;
    int start = t * PER;
    int local[PER];
    int sum = 0;
#pragma unroll
    for (int i = 0; i < PER; ++i) {
        int idx = start + i;
        int v = (idx < n) ? counts[idx] : 0;
        local[i] = sum;
        sum += v;
    }
    int lane = t & 63, wid = t >> 6;
    int inc = sum;
#pragma unroll
    for (int d = 1; d < 64; d <<= 1) {
        int up = __shfl_up(inc, d);
        if (lane >= d) inc += up;
    }
    __shared__ int wsum[16], woff[16];
    if (lane == 63) wsum[wid] = inc;
    __syncthreads();
    if (t < 16) {
        int acc = 0;
        for (int j = 0; j < 16; ++j) if (j < t) acc += wsum[j];
        woff[t] = acc;
    }
    __syncthreads();
    int base = woff[wid] + (inc - sum);
#pragma unroll
    for (int i = 0; i < PER; ++i) {
        int idx = start + i;
        if (idx < n) {
            uint_t off = (uint_t)(base + local[i]);
            obnd[idx] = make_uint2(off, off + (uint_t)cnt_p[idx]);
        }
    }
    if (t == 1023) {
        uint_t tot = (uint_t)(base + sum);
        obnd[n] = make_uint2(tot, tot);
    }
}

__global__ __launch_bounds__(1024) void scat_kernel(const int* __restrict__ ei,
                                                    const float* __restrict__ ew,
                                                    const uint_t* __restrict__ bh,
                                                    const uint2* __restrict__ obnd,
                                                    uint2* __restrict__ es, int E) {
    __shared__ uint_t cur[N_NODES];
    int b = blockIdx.x;
    const uint_t* pref = bh + (size_t)b * N_NODES;
    for (int i = threadIdx.x * 4; i < N_NODES; i += 4096)
        *(uint4*)&cur[i] = *(const uint4*)&pref[i];
    __syncthreads();
    int epb = (E + HBLK - 1) / HBLK;
    int e0 = b * epb, e1 = min(e0 + epb, E);
    for (int e = e0 + threadIdx.x; e < e1; e += 1024) {
        int src = ei[e];
        int dst = ei[E + e];
        float w = ew[e];
        if (w > 0.0f) {
            uint_t old = atomicAdd(&cur[dst], 1u);
            uint_t pos = obnd[dst].x + (old & 0xffffu);
            es[pos] = make_uint2((uint_t)src, __float_as_uint(w));
        } else if (w < 0.0f) {
            uint_t old = atomicAdd(&cur[dst], 0x10000u);
            uint_t pos = obnd[dst].y + (old >> 16);
            es[pos] = make_uint2((uint_t)src, __float_as_uint(-w));
        }
    }
}

// ---------------- all casts in one launch ----------------
// grid = (2500, 7): tasks 0..5 = conv weight castpad (256 blocks used), task 6 = x cast.
__global__ void prep_kernel(const float* __restrict__ W0p, const float* __restrict__ W0n,
                            const float* __restrict__ W1p, const float* __restrict__ W1n,
                            const float* __restrict__ W2p, const float* __restrict__ W2n,
                            const float* __restrict__ x,
                            ushort_t* __restrict__ wcast, ushort_t* __restrict__ xb) {
    int task = blockIdx.y;
    if (task < 6) {
        if (blockIdx.x >= 256) return;
        const float* W = (task == 0) ? W0p : (task == 1) ? W0n : (task == 2) ? W1p
                       : (task == 3) ? W1n : (task == 4) ? W2p : W2n;
        int K2 = (task < 2) ? 400 : 512;
        int idx = blockIdx.x * 256 + threadIdx.x;       // < 65536
        int row = idx >> 9;
        int col = idx & (KSTRIDE - 1);
        wcast[task * 65536 + idx] = (col < K2) ? f2bf(W[(size_t)row * K2 + col]) : (ushort_t)0;
    } else {
        int i = (blockIdx.x * 256 + threadIdx.x) * 4;
        if (i >= N_NODES * FEAT) return;
        float4 v = *(const float4*)&x[i];
        ushort4 o;
        o.x = f2bf(v.x); o.y = f2bf(v.y); o.z = f2bf(v.z); o.w = f2bf(v.w);
        *(ushort4*)&xb[i] = o;
    }
}

// ---------------- signed aggregation: 4 waves/block, one node per wave ----------------
template <int D>
__global__ __launch_bounds__(256) void agg_kernel(
        const ushort_t* __restrict__ hb,
        const uint2* __restrict__ obnd,
        const uint2* __restrict__ es,
        ushort_t* __restrict__ Ap, ushort_t* __restrict__ An) {
    constexpr int ACT = D / 4;
    int lane = threadIdx.x & 63;
    int wv   = threadIdx.x >> 6;
    int n = blockIdx.x * 4 + wv;
    int c0 = min(lane, ACT - 1) * 4;
    uint2 ob = obnd[n];
    uint_t off = ob.x, mid = ob.y, end = obnd[n + 1].x;

    float ap[4] = {0.f, 0.f, 0.f, 0.f};
    float an[4] = {0.f, 0.f, 0.f, 0.f};

#pragma unroll 1
    for (int phase = 0; phase < 2; ++phase) {
        uint_t lo = phase ? mid : off;
        uint_t hi = phase ? end : mid;
        float* acc = phase ? an : ap;
#pragma unroll 1
        for (uint_t base = lo; base < hi; base += 64) {
            int cnt = (int)min(64u, hi - base);
            uint2 rec = es[base + (uint_t)min(lane, cnt - 1)];
            int i = 0;
#pragma unroll 1
            for (; i + 8 <= cnt; i += 8) {
                int s[8]; float w[8]; uint2 p[8];
#pragma unroll
                for (int j = 0; j < 8; ++j) {
                    s[j] = __shfl((int)rec.x, i + j);
                    w[j] = __uint_as_float((uint_t)__shfl((int)rec.y, i + j));
                }
#pragma unroll
                for (int j = 0; j < 8; ++j) p[j] = *(const uint2*)&hb[(size_t)s[j] * D + c0];
#pragma unroll
                for (int j = 0; j < 8; ++j) {
                    const ushort_t* q = (const ushort_t*)&p[j];
#pragma unroll
                    for (int c = 0; c < 4; ++c) acc[c] = fmaf(w[j], bf2f(q[c]), acc[c]);
                }
            }
#pragma unroll 1
            for (; i < cnt; ++i) {
                int s = __shfl((int)rec.x, i);
                float w = __uint_as_float((uint_t)__shfl((int)rec.y, i));
                uint2 pk = *(const uint2*)&hb[(size_t)s * D + c0];
                const ushort_t* q = (const ushort_t*)&pk;
#pragma unroll
                for (int c = 0; c < 4; ++c) acc[c] = fmaf(w, bf2f(q[c]), acc[c]);
            }
        }
    }

    size_t rb = (size_t)n * KSTRIDE;
    if (lane < ACT) {
        float dp = fmaxf((float)(mid - off), 1.0f);
        float dn = fmaxf((float)(end - mid), 1.0f);
        uint2 pk = *(const uint2*)&hb[(size_t)n * D + c0];
        const ushort_t* p = (const ushort_t*)&pk;
        ushort4 os = {p[0], p[1], p[2], p[3]};
        ushort4 op, on;
        op.x = f2bf(ap[0] / dp); op.y = f2bf(ap[1] / dp);
        op.z = f2bf(ap[2] / dp); op.w = f2bf(ap[3] / dp);
        on.x = f2bf(an[0] / dn); on.y = f2bf(an[1] / dn);
        on.z = f2bf(an[2] / dn); on.w = f2bf(an[3] / dn);
        *(ushort4*)&Ap[rb + c0] = op;
        *(ushort4*)&An[rb + c0] = on;
        *(ushort4*)&Ap[rb + D + c0] = os;
        *(ushort4*)&An[rb + D + c0] = os;
    }
    if (D == 200 && lane >= 50 && lane < 54) {   // zero pad cols 400..415
        ushort4 z = {0, 0, 0, 0};
        *(ushort4*)&Ap[rb + 400 + (lane - 50) * 4] = z;
        *(ushort4*)&An[rb + 400 + (lane - 50) * 4] = z;
    }
}

// ---------------- conv linear via MFMA, async LDS staging + double buffer ----------------
// grid.x = M/64, grid.y = 2 (branch). block = 256 (4 waves). Tile 64x128x32.
template <int KSTEPS, bool LEAKY>
__global__ __launch_bounds__(256) void conv_mfma(
        const ushort_t* __restrict__ Ap, const ushort_t* __restrict__ An,
        const ushort_t* __restrict__ Wpb, const ushort_t* __restrict__ Wnb,
        const float* __restrict__ bp, const float* __restrict__ bn,
        ushort_t* __restrict__ hout) {
    __shared__ __align__(16) ushort_t As[2][64 * 32];    // 2 x 4 KB
    __shared__ __align__(16) ushort_t Bs[2][128 * 32];   // 2 x 8 KB
    int mBase = blockIdx.x * 64;
    bool neg = (blockIdx.y != 0);
    const ushort_t* A    = neg ? An : Ap;
    const ushort_t* W    = neg ? Wnb : Wpb;
    const float*    bias = neg ? bn : bp;
    int tid  = threadIdx.x;
    int lane = tid & 63;
    int wv   = tid >> 6;
    int r    = lane & 15;
    int quad = lane >> 4;

    // per-thread global source offsets (16 B each); LDS dst = wave-uniform base + lane*16B
    int rowA = tid >> 2, colA = (tid & 3) * 8;
    const ushort_t* gA  = A + (size_t)(mBase + rowA) * KSTRIDE + colA;
    const ushort_t* gB0 = W + (size_t)rowA * KSTRIDE + colA;
    const ushort_t* gB1 = W + (size_t)(rowA + 64) * KSTRIDE + colA;

    f32x4 acc[8];
#pragma unroll
    for (int j = 0; j < 8; ++j) acc[j] = (f32x4){0.f, 0.f, 0.f, 0.f};

    // prologue: stage step 0 into buffer 0
    __builtin_amdgcn_global_load_lds(GAS(gA),  LAS(&As[0][wv * 512]), 16, 0, 0);
    __builtin_amdgcn_global_load_lds(GAS(gB0), LAS(&Bs[0][wv * 512]), 16, 0, 0);
    __builtin_amdgcn_global_load_lds(GAS(gB1), LAS(&Bs[0][2048 + wv * 512]), 16, 0, 0);

    for (int kt = 0; kt < KSTEPS; ++kt) {
        int cur = kt & 1;
        __syncthreads();   // drains this step's loads (vmcnt(0)) and syncs waves
        if (kt + 1 < KSTEPS) {
            int kB = (kt + 1) * 32;
            __builtin_amdgcn_global_load_lds(GAS(gA + kB),  LAS(&As[cur ^ 1][wv * 512]), 16, 0, 0);
            __builtin_amdgcn_global_load_lds(GAS(gB0 + kB), LAS(&Bs[cur ^ 1][wv * 512]), 16, 0, 0);
            __builtin_amdgcn_global_load_lds(GAS(gB1 + kB), LAS(&Bs[cur ^ 1][2048 + wv * 512]), 16, 0, 0);
        }
        bf16x8 a = *(const bf16x8*)&As[cur][(wv * 16 + r) * 32 + quad * 8];
#pragma unroll
        for (int j = 0; j < 8; ++j) {
            bf16x8 b = *(const bf16x8*)&Bs[cur][(j * 16 + r) * 32 + quad * 8];
            acc[j] = __builtin_amdgcn_mfma_f32_16x16x32_bf16(a, b, acc[j], 0, 0, 0);
        }
    }
    int colOff = neg ? HALF : 0;
#pragma unroll
    for (int j = 0; j < 8; ++j) {
        int c = j * 16 + r;
        float bv = bias[c];
#pragma unroll
        for (int reg = 0; reg < 4; ++reg) {
            int m = mBase + wv * 16 + quad * 4 + reg;
            float v = acc[j][reg] + bv;
            if (LEAKY) v = (v > 0.0f) ? v : 0.01f * v;
            hout[(size_t)m * HID + colOff + c] = f2bf(v);
        }
    }
}

// ---------------- readout via MFMA, split-K; Wr converted inline fp32->bf16 ----------------
__global__ __launch_bounds__(256) void readout_mfma(
        const ushort_t* __restrict__ h, const float* __restrict__ Wr,
        float* __restrict__ g_ws) {
    __shared__ __align__(16) ushort_t As[64 * 32];
    __shared__ __align__(16) ushort_t Bs[64 * 32];
    int nBase  = blockIdx.x * 64;
    int kStart = blockIdx.y * 800;
    int tid  = threadIdx.x;
    int lane = tid & 63;
    int wv   = tid >> 6;
    int r    = lane & 15;
    int quad = lane >> 4;

    f32x4 acc[4];
#pragma unroll
    for (int j = 0; j < 4; ++j) acc[j] = (f32x4){0.f, 0.f, 0.f, 0.f};

    for (int kt = 0; kt < 25; ++kt) {
        int kBase = kStart + kt * 32;
        int lin = tid * 8;
        int row = lin >> 5, col = lin & 31;
        *(uint4*)&As[lin] = *(const uint4*)&h[(size_t)row * KREAD + kBase + col];
        {
            const float* wp = &Wr[(size_t)(nBase + row) * KREAD + kBase + col];
            float4 f0 = *(const float4*)&wp[0];
            float4 f1 = *(const float4*)&wp[4];
            ushort4 b0, b1;
            b0.x = f2bf(f0.x); b0.y = f2bf(f0.y); b0.z = f2bf(f0.z); b0.w = f2bf(f0.w);
            b1.x = f2bf(f1.x); b1.y = f2bf(f1.y); b1.z = f2bf(f1.z); b1.w = f2bf(f1.w);
            *(ushort4*)&Bs[lin]     = b0;
            *(ushort4*)&Bs[lin + 4] = b1;
        }
        __syncthreads();
        bf16x8 a = *(const bf16x8*)&As[(wv * 16 + r) * 32 + quad * 8];
#pragma unroll
        for (int j = 0; j < 4; ++j) {
            bf16x8 b = *(const bf16x8*)&Bs[(j * 16 + r) * 32 + quad * 8];
            acc[j] = __builtin_amdgcn_mfma_f32_16x16x32_bf16(a, b, acc[j], 0, 0, 0);
        }
        __syncthreads();
    }
#pragma unroll
    for (int j = 0; j < 4; ++j) {
        int c = nBase + j * 16 + r;
#pragma unroll
        for (int reg = 0; reg < 4; ++reg) {
            int g = wv * 16 + quad * 4 + reg;
            atomicAdd(&g_ws[g * HID + c], acc[j][reg]);
        }
    }
}

// ---------------- final ----------------
__global__ void final_kernel(const float* __restrict__ g_ws, const float* __restrict__ br,
                             const float* __restrict__ Wl, const float* __restrict__ bl,
                             float* __restrict__ out) {
    int g = blockIdx.x;
    int c = threadIdx.x;
    float v = (g_ws[g * HID + c] + br[c]) * Wl[c];
#pragma unroll
    for (int d = 32; d > 0; d >>= 1) v += __shfl_down(v, d);
    __shared__ float s[4];
    if ((c & 63) == 0) s[c >> 6] = v;
    __syncthreads();
    if (c == 0) out[g] = s[0] + s[1] + s[2] + s[3] + bl[0];
}

// ---------------- launch ----------------
extern "C" void kernel_launch(void* const* d_in, const int* in_sizes, int n_in,
                              void* d_out, int out_size, void* d_ws, size_t ws_size,
                              hipStream_t stream) {
    const float* x  = (const float*)d_in[0];
    const int*   ei = (const int*)d_in[1];
    const float* ew = (const float*)d_in[2];
    const float* Wp0 = (const float*)d_in[4];
    const float* bp0 = (const float*)d_in[5];
    const float* Wn0 = (const float*)d_in[6];
    const float* bn0 = (const float*)d_in[7];
    const float* Wp1 = (const float*)d_in[8];
    const float* bp1 = (const float*)d_in[9];
    const float* Wn1 = (const float*)d_in[10];
    const float* bn1 = (const float*)d_in[11];
    const float* Wp2 = (const float*)d_in[12];
    const float* bp2 = (const float*)d_in[13];
    const float* Wn2 = (const float*)d_in[14];
    const float* bn2 = (const float*)d_in[15];
    const float* Wr  = (const float*)d_in[16];
    const float* br  = (const float*)d_in[17];
    const float* Wl  = (const float*)d_in[18];
    const float* bl  = (const float*)d_in[19];
    const int E = in_sizes[1] / 2;   // 409600

    // ---- workspace layout (bytes) ----
    char* ws = (char*)d_ws;
    float*    g_ws   = (float*)(ws + 0);              // 65536 (memset region)
    uint_t*   bh     = (uint_t*)(ws + 65536);         // 128*12800*4 -> 6619136
    int*      counts = (int*)(ws + 6619136);          // -> 6670336
    int*      cnt_p  = (int*)(ws + 6670336);          // -> 6721536
    uint2*    obnd   = (uint2*)(ws + 6721536);        // -> 6824000
    uint2*    es     = (uint2*)(ws + 6824000);        // E*8 -> 10100800
    ushort_t* Ap     = (ushort_t*)(ws + 10100800);    // 12800*512 bf16 -> 23208000
    ushort_t* An     = (ushort_t*)(ws + 23208000);    // -> 36315200
    ushort_t* hA     = (ushort_t*)(ws + 36315200);    // 12800*256 bf16 -> 42868800
    ushort_t* hB     = (ushort_t*)(ws + 42868800);    // -> 49422400
    ushort_t* wcast  = (ushort_t*)(ws + 49422400);    // 6*65536 bf16 -> 50208832
    ushort_t* xb     = (ushort_t*)(ws + 50208832);    // 12800*200 bf16 -> 55328832

    ushort_t* w0p = wcast + 0 * 65536;
    ushort_t* w0n = wcast + 1 * 65536;
    ushort_t* w1p = wcast + 2 * 65536;
    ushort_t* w1n = wcast + 3 * 65536;
    ushort_t* w2p = wcast + 4 * 65536;
    ushort_t* w2n = wcast + 5 * 65536;

    hipMemsetAsync(g_ws, 0, 65536, stream);

    // CSR build
    hipLaunchKernelGGL(bhist_kernel, dim3(HBLK), dim3(1024), 0, stream, ei, ew, bh, E);
    hipLaunchKernelGGL(colpref_kernel, dim3((N_NODES + 255) / 256), dim3(256), 0, stream,
                       bh, counts, cnt_p);
    hipLaunchKernelGGL(scan_kernel, dim3(1), dim3(1024), 0, stream, counts, cnt_p, obnd, N_NODES);
    hipLaunchKernelGGL(scat_kernel, dim3(HBLK), dim3(1024), 0, stream, ei, ew, bh, obnd, es, E);

    // all casts in one launch
    hipLaunchKernelGGL(prep_kernel, dim3(2500, 7), dim3(256), 0, stream,
                       Wp0, Wn0, Wp1, Wn1, Wp2, Wn2, x, wcast, xb);

    // layer 0: in = xb (bf16, D=200), KSTEPS = 13 (covers padded 416)
    hipLaunchKernelGGL((agg_kernel<FEAT>), dim3(N_NODES / 4), dim3(256), 0, stream,
                       xb, obnd, es, Ap, An);
    hipLaunchKernelGGL((conv_mfma<13, true>), dim3(N_NODES / 64, 2), dim3(256), 0, stream,
                       Ap, An, w0p, w0n, bp0, bn0, hA);
    // layer 1
    hipLaunchKernelGGL((agg_kernel<HID>), dim3(N_NODES / 4), dim3(256), 0, stream,
                       hA, obnd, es, Ap, An);
    hipLaunchKernelGGL((conv_mfma<16, true>), dim3(N_NODES / 64, 2), dim3(256), 0, stream,
                       Ap, An, w1p, w1n, bp1, bn1, hB);
    // layer 2
    hipLaunchKernelGGL((agg_kernel<HID>), dim3(N_NODES / 4), dim3(256), 0, stream,
                       hB, obnd, es, Ap, An);
    hipLaunchKernelGGL((conv_mfma<16, false>), dim3(N_NODES / 64, 2), dim3(256), 0, stream,
                       Ap, An, w2p, w2n, bp2, bn2, hA);

    // readout + final
    hipLaunchKernelGGL(readout_mfma, dim3(4, 64), dim3(256), 0, stream, hA, Wr, g_ws);
    hipLaunchKernelGGL(final_kernel, dim3(NUM_GRAPHS), dim3(256), 0, stream,
                       g_ws, br, Wl, bl, (float*)d_out);
}